// Round 2
// baseline (889.626 us; speedup 1.0000x reference)
//
#include <hip/hip_runtime.h>

typedef unsigned short u16;
typedef unsigned int u32;

__device__ __forceinline__ float bf2f(u32 u) {
    return __uint_as_float(u << 16);
}
__device__ __forceinline__ u16 f2bf(float f) {
    u32 x = __float_as_uint(f);
    u32 r = (x + 0x7fffu + ((x >> 16) & 1u)) >> 16;   // round-nearest-even
    return (u16)r;
}

// ---------------------------------------------------------------- GEMM
// C[M,Ncol] = A[M,K] @ B[K,Ncol]; A is f32 (AF32) or bf16; B is f32; C bf16.
// fp32 accum. 64x64 tile, BK=32, 256 threads, 4x4 per thread.
template<bool AF32>
__global__ __launch_bounds__(256) void gemm_k(
    const void* __restrict__ Ap, const float* __restrict__ B,
    u16* __restrict__ C, int M, int K, int Ncol)
{
    __shared__ float As[32][64];   // As[k][m] (transposed)
    __shared__ float Bs[32][64];   // Bs[k][n]
    const int t  = threadIdx.x;
    const int m0 = blockIdx.y * 64, n0 = blockIdx.x * 64;
    const int tx = t & 15, ty = t >> 4;
    const int am = t >> 2,  ak = (t & 3) * 8;   // A staging: row am, k off ak..ak+7
    const int bk = t >> 3,  bn = (t & 7) * 8;   // B staging: k row bk, col bn..bn+7
    float acc[4][4] = {};
    const int ntile = (K + 31) >> 5;

    for (int kt = 0; kt < ntile; ++kt) {
        const int k0 = kt << 5;
        // stage A
        {
            const int gm = m0 + am;
            if constexpr (AF32) {
                const float* A = (const float*)Ap;
#pragma unroll
                for (int j = 0; j < 8; ++j) {
                    const int gk = k0 + ak + j;
                    float v = 0.f;
                    if (gm < M && gk < K) v = A[(size_t)gm * K + gk];
                    As[ak + j][am] = v;
                }
            } else {
                const u16* A = (const u16*)Ap;
                if (gm < M && (k0 + ak + 8) <= K) {
                    const int4 r = *reinterpret_cast<const int4*>(A + (size_t)gm * K + k0 + ak);
                    const u32 rr[4] = {(u32)r.x, (u32)r.y, (u32)r.z, (u32)r.w};
#pragma unroll
                    for (int q = 0; q < 4; ++q) {
                        As[ak + 2*q    ][am] = bf2f(rr[q] & 0xffffu);
                        As[ak + 2*q + 1][am] = bf2f(rr[q] >> 16);
                    }
                } else {
#pragma unroll
                    for (int j = 0; j < 8; ++j) {
                        const int gk = k0 + ak + j;
                        float v = 0.f;
                        if (gm < M && gk < K) v = bf2f((u32)A[(size_t)gm * K + gk]);
                        As[ak + j][am] = v;
                    }
                }
            }
        }
        // stage B (f32, Ncol always multiple of 64)
        {
            const int gk = k0 + bk;
            if (gk < K) {
                const float4 r0 = *reinterpret_cast<const float4*>(B + (size_t)gk * Ncol + n0 + bn);
                const float4 r1 = *reinterpret_cast<const float4*>(B + (size_t)gk * Ncol + n0 + bn + 4);
                Bs[bk][bn + 0] = r0.x; Bs[bk][bn + 1] = r0.y;
                Bs[bk][bn + 2] = r0.z; Bs[bk][bn + 3] = r0.w;
                Bs[bk][bn + 4] = r1.x; Bs[bk][bn + 5] = r1.y;
                Bs[bk][bn + 6] = r1.z; Bs[bk][bn + 7] = r1.w;
            } else {
#pragma unroll
                for (int j = 0; j < 8; ++j) Bs[bk][bn + j] = 0.f;
            }
        }
        __syncthreads();
#pragma unroll
        for (int kk = 0; kk < 32; ++kk) {
            const float4 av = *reinterpret_cast<const float4*>(&As[kk][ty * 4]);
            const float4 bv = *reinterpret_cast<const float4*>(&Bs[kk][tx * 4]);
            const float a4[4] = {av.x, av.y, av.z, av.w};
            const float b4[4] = {bv.x, bv.y, bv.z, bv.w};
#pragma unroll
            for (int i = 0; i < 4; ++i)
#pragma unroll
                for (int j = 0; j < 4; ++j) acc[i][j] += a4[i] * b4[j];
        }
        __syncthreads();
    }
#pragma unroll
    for (int i = 0; i < 4; ++i) {
        const int gm = m0 + ty * 4 + i;
        if (gm < M) {
            u32 p0 = (u32)f2bf(acc[i][0]) | ((u32)f2bf(acc[i][1]) << 16);
            u32 p1 = (u32)f2bf(acc[i][2]) | ((u32)f2bf(acc[i][3]) << 16);
            uint2 w = make_uint2(p0, p1);
            *reinterpret_cast<uint2*>(C + (size_t)gm * Ncol + n0 + tx * 4) = w;
        }
    }
}

// ---------------------------------------------------------------- logits
// al_s[n,h] = sum_c h[n,h,c]*a_src[h,c]; one wave per node. h bf16, a_* f32.
template<int CH, int C>
__global__ __launch_bounds__(256) void logits_k(
    const u16* __restrict__ h, const float* __restrict__ a_s,
    const float* __restrict__ a_d, float* __restrict__ als,
    float* __restrict__ ald, int N)
{
    constexpr int HH = CH / C;
    constexpr int Kc = CH / 64;
    const int lane = threadIdx.x & 63;
    const int n = blockIdx.x * 4 + (threadIdx.x >> 6);
    if (n >= N) return;
    const int ch0 = Kc * lane;
    float vv[Kc];
    const u16* hp = h + (size_t)n * CH + ch0;
    if constexpr (Kc == 8) {
        const int4 r = *reinterpret_cast<const int4*>(hp);
        const u32 rr[4] = {(u32)r.x, (u32)r.y, (u32)r.z, (u32)r.w};
#pragma unroll
        for (int q = 0; q < 4; ++q) { vv[2*q] = bf2f(rr[q] & 0xffffu); vv[2*q+1] = bf2f(rr[q] >> 16); }
    } else {
        const u32 r = *reinterpret_cast<const u32*>(hp);
        vv[0] = bf2f(r & 0xffffu); vv[1] = bf2f(r >> 16);
    }
    float ps = 0.f, pd = 0.f;
#pragma unroll
    for (int j = 0; j < Kc; ++j) {
        ps += vv[j] * a_s[ch0 + j];
        pd += vv[j] * a_d[ch0 + j];
    }
    constexpr int Gs = 64 / HH;   // lanes per head group
#pragma unroll
    for (int off = Gs >> 1; off; off >>= 1) {
        ps += __shfl_xor(ps, off, 64);
        pd += __shfl_xor(pd, off, 64);
    }
    const int hd = ch0 / C;
    if ((lane & (Gs - 1)) == 0) {
        als[(size_t)n * HH + hd] = ps;
        ald[(size_t)n * HH + hd] = pd;
    }
}

// ---------------------------------------------------------------- CSR build
__global__ void count_k(const int* __restrict__ edst, int* __restrict__ cnt, int E_, int N_)
{
    const int i = blockIdx.x * 256 + threadIdx.x;
    if (i >= E_ + N_) return;
    const int d = (i < E_) ? edst[i] : (i - E_);
    atomicAdd(&cnt[d], 1);
}

#define SCAN_B 256
__global__ void scan1_k(const int* __restrict__ cnt, int* __restrict__ part,
                        int* __restrict__ bsum, int n)
{
    __shared__ int sm[SCAN_B];
    const int idx = blockIdx.x * SCAN_B + threadIdx.x;
    int v = (idx < n) ? cnt[idx] : 0;
    sm[threadIdx.x] = v;
    __syncthreads();
    for (int off = 1; off < SCAN_B; off <<= 1) {
        int t2 = (threadIdx.x >= off) ? sm[threadIdx.x - off] : 0;
        __syncthreads();
        sm[threadIdx.x] += t2;
        __syncthreads();
    }
    if (idx < n) part[idx] = sm[threadIdx.x];
    if (threadIdx.x == SCAN_B - 1) bsum[blockIdx.x] = sm[threadIdx.x];
}

__global__ void scan2_k(int* __restrict__ bsum, int nb)
{
    __shared__ int sm[SCAN_B];
    const int t = threadIdx.x;
    int v = (t < nb) ? bsum[t] : 0;
    sm[t] = v;
    __syncthreads();
    for (int off = 1; off < SCAN_B; off <<= 1) {
        int t2 = (t >= off) ? sm[t - off] : 0;
        __syncthreads();
        sm[t] += t2;
        __syncthreads();
    }
    if (t < nb) bsum[t] = sm[t] - v;   // exclusive
}

__global__ void scan3_k(const int* __restrict__ part, const int* __restrict__ boff,
                        int* __restrict__ offs, int n)
{
    const int idx = blockIdx.x * SCAN_B + threadIdx.x;
    if (idx < n) offs[idx + 1] = part[idx] + boff[idx / SCAN_B];
    if (idx == 0) offs[0] = 0;
}

__global__ void scatter_k(const int* __restrict__ esrc, const int* __restrict__ edst,
                          const int* __restrict__ offs, int* __restrict__ fill,
                          int* __restrict__ csr, int E_, int N_)
{
    const int i = blockIdx.x * 256 + threadIdx.x;
    if (i >= E_ + N_) return;
    int s, d;
    if (i < E_) { s = esrc[i]; d = edst[i]; } else { s = d = i - E_; }
    const int pos = offs[d] + atomicAdd(&fill[d], 1);
    csr[pos] = s;
}

// ---------------------------------------------------------------- softmax+aggregate+BN(+ReLU)
// one wave per dst node; atomic-free segmented softmax & weighted gather.
// h bf16; BN params f32; output bf16.
template<int CH, int C, bool RELU>
__global__ __launch_bounds__(256) void agg_k(
    const u16* __restrict__ hsrc, const int* __restrict__ offs,
    const int* __restrict__ csr, const float* __restrict__ als,
    const float* __restrict__ ald, const float* __restrict__ bias,
    const float* __restrict__ gam, const float* __restrict__ bet,
    const float* __restrict__ rmean, const float* __restrict__ rvar,
    u16* __restrict__ outp, int N)
{
    constexpr int HH = CH / C;
    constexpr int Kc = CH / 64;
    const int lane = threadIdx.x & 63;
    const int dst = blockIdx.x * 4 + (threadIdx.x >> 6);
    if (dst >= N) return;
    const int ch0 = Kc * lane;
    const int hd = ch0 / C;          // head of this lane's channels (constant)

    float adv[HH];
#pragma unroll
    for (int h = 0; h < HH; ++h) adv[h] = ald[(size_t)dst * HH + h];

    const int rs = offs[dst], re = offs[dst + 1];

    // pass 1: per-head max
    float m[HH];
#pragma unroll
    for (int h = 0; h < HH; ++h) m[h] = -1e30f;
    for (int s = rs + lane; s < re; s += 64) {
        const int sn = csr[s];
        if constexpr (HH == 4) {
            const float4 av = *reinterpret_cast<const float4*>(&als[(size_t)sn * 4]);
            const float ev[4] = {av.x + adv[0], av.y + adv[1], av.z + adv[2], av.w + adv[3]};
#pragma unroll
            for (int h = 0; h < 4; ++h) {
                float e = ev[h]; e = (e > 0.f) ? e : 0.2f * e;
                m[h] = fmaxf(m[h], e);
            }
        } else {
            float e = als[sn] + adv[0]; e = (e > 0.f) ? e : 0.2f * e;
            m[0] = fmaxf(m[0], e);
        }
    }
#pragma unroll
    for (int h = 0; h < HH; ++h)
#pragma unroll
        for (int off = 32; off; off >>= 1) m[h] = fmaxf(m[h], __shfl_xor(m[h], off, 64));

    // pass 2: per-head denom
    float smv[HH];
#pragma unroll
    for (int h = 0; h < HH; ++h) smv[h] = 0.f;
    for (int s = rs + lane; s < re; s += 64) {
        const int sn = csr[s];
        if constexpr (HH == 4) {
            const float4 av = *reinterpret_cast<const float4*>(&als[(size_t)sn * 4]);
            const float ev[4] = {av.x + adv[0], av.y + adv[1], av.z + adv[2], av.w + adv[3]};
#pragma unroll
            for (int h = 0; h < 4; ++h) {
                float e = ev[h]; e = (e > 0.f) ? e : 0.2f * e;
                smv[h] += __expf(e - m[h]);
            }
        } else {
            float e = als[sn] + adv[0]; e = (e > 0.f) ? e : 0.2f * e;
            smv[0] += __expf(e - m[0]);
        }
    }
#pragma unroll
    for (int h = 0; h < HH; ++h)
#pragma unroll
        for (int off = 32; off; off >>= 1) smv[h] += __shfl_xor(smv[h], off, 64);
    float inv[HH];
#pragma unroll
    for (int h = 0; h < HH; ++h) inv[h] = 1.f / (smv[h] + 1e-16f);

    // pass 3: weighted gather (sequential over edges, parallel over channels)
    float acc[Kc] = {};
    for (int s = rs; s < re; ++s) {
        const int sn = csr[s];
        float e = als[(size_t)sn * HH + hd] + adv[hd];
        e = (e > 0.f) ? e : 0.2f * e;
        const float a = __expf(e - m[hd]) * inv[hd];
        const u16* hp = hsrc + (size_t)sn * CH + ch0;
        if constexpr (Kc == 8) {
            const int4 r = *reinterpret_cast<const int4*>(hp);
            const u32 rr[4] = {(u32)r.x, (u32)r.y, (u32)r.z, (u32)r.w};
#pragma unroll
            for (int q = 0; q < 4; ++q) {
                acc[2*q]   += a * bf2f(rr[q] & 0xffffu);
                acc[2*q+1] += a * bf2f(rr[q] >> 16);
            }
        } else {
            const u32 r = *reinterpret_cast<const u32*>(hp);
            acc[0] += a * bf2f(r & 0xffffu);
            acc[1] += a * bf2f(r >> 16);
        }
    }

    // epilogue: +bias, BN (eval), optional ReLU, store bf16
    u16 ob[Kc];
#pragma unroll
    for (int j = 0; j < Kc; ++j) {
        const int ch = ch0 + j;
        const float scale = gam[ch] * rsqrtf(rvar[ch] + 1e-5f);
        float val = (acc[j] + bias[ch] - rmean[ch]) * scale + bet[ch];
        if (RELU) val = fmaxf(val, 0.f);
        ob[j] = f2bf(val);
    }
    u16* op = outp + (size_t)dst * CH + ch0;
    if constexpr (Kc == 8) {
        int4 w;
        w.x = (int)((u32)ob[0] | ((u32)ob[1] << 16));
        w.y = (int)((u32)ob[2] | ((u32)ob[3] << 16));
        w.z = (int)((u32)ob[4] | ((u32)ob[5] << 16));
        w.w = (int)((u32)ob[6] | ((u32)ob[7] << 16));
        *reinterpret_cast<int4*>(op) = w;
    } else {
        *reinterpret_cast<u32*>(op) = (u32)ob[0] | ((u32)ob[1] << 16);
    }
}

// ---------------------------------------------------------------- pool
// one block (128 threads) per graph; binary search sorted batch for bounds.
// h3 bf16, out f32.
__global__ __launch_bounds__(128) void pool_k(
    const u16* __restrict__ h3, const int* __restrict__ batch,
    float* __restrict__ out, int N)
{
    const int g = blockIdx.x;
    const int t = threadIdx.x;
    int lo = 0, hi = N;
    while (lo < hi) { int mid = (lo + hi) >> 1; if (batch[mid] < g) lo = mid + 1; else hi = mid; }
    const int s0 = lo;
    lo = 0; hi = N;
    while (lo < hi) { int mid = (lo + hi) >> 1; if (batch[mid] < g + 1) lo = mid + 1; else hi = mid; }
    const int s1 = lo;
    float sum = 0.f, mx = -1e30f;
    for (int n = s0; n < s1; ++n) {
        const float v = bf2f((u32)h3[(size_t)n * 128 + t]);
        sum += v;
        mx = fmaxf(mx, v);
    }
    const int cnt = s1 - s0;
    out[(size_t)g * 256 + t]       = cnt ? sum / (float)cnt : 0.f;
    out[(size_t)g * 256 + 128 + t] = cnt ? mx : 0.f;
}

// ---------------------------------------------------------------- launch
extern "C" void kernel_launch(void* const* d_in, const int* in_sizes, int n_in,
                              void* d_out, int out_size, void* d_ws, size_t ws_size,
                              hipStream_t stream)
{
    const float* x   = (const float*)d_in[0];
    const int* ei    = (const int*)d_in[1];
    const int* batch = (const int*)d_in[2];
    const float* W1  = (const float*)d_in[3];
    const float* as1 = (const float*)d_in[4];
    const float* ad1 = (const float*)d_in[5];
    const float* b1  = (const float*)d_in[6];
    const float* g1  = (const float*)d_in[7];
    const float* bt1 = (const float*)d_in[8];
    const float* rm1 = (const float*)d_in[9];
    const float* rv1 = (const float*)d_in[10];
    const float* W2  = (const float*)d_in[11];
    const float* as2 = (const float*)d_in[12];
    const float* ad2 = (const float*)d_in[13];
    const float* b2  = (const float*)d_in[14];
    const float* g2  = (const float*)d_in[15];
    const float* bt2 = (const float*)d_in[16];
    const float* rm2 = (const float*)d_in[17];
    const float* rv2 = (const float*)d_in[18];
    const float* W3  = (const float*)d_in[19];
    const float* as3 = (const float*)d_in[20];
    const float* ad3 = (const float*)d_in[21];
    const float* b3  = (const float*)d_in[22];
    const float* g3  = (const float*)d_in[23];
    const float* bt3 = (const float*)d_in[24];
    const float* rm3 = (const float*)d_in[25];
    const float* rv3 = (const float*)d_in[26];

    const int Nn = in_sizes[2];           // 50000
    const int Ee = in_sizes[1] / 2;       // 400000
    const int ET = Ee + Nn;               // + self-loops
    const int FIN = in_sizes[0] / Nn;     // 75
    const int Gg = out_size / 256;        // 512

    // workspace carve-up (256B aligned)
    char* ws = (char*)d_ws;
    size_t o = 0;
    auto alc = [&](size_t bytes) { size_t r = o; o = (o + bytes + 255) & ~(size_t)255; return r; };
    u16*  hA   = (u16*)(ws + alc((size_t)Nn * 512 * 2));
    u16*  hB   = (u16*)(ws + alc((size_t)Nn * 512 * 2));
    float* als = (float*)(ws + alc((size_t)Nn * 4 * 4));
    float* ald = (float*)(ws + alc((size_t)Nn * 4 * 4));
    int*  cnt  = (int*)(ws + alc((size_t)2 * Nn * 4));   // cnt + fill adjacent
    int*  fill = cnt + Nn;
    int*  offs = (int*)(ws + alc((size_t)(Nn + 1) * 4));
    int*  part = (int*)(ws + alc((size_t)Nn * 4));
    int*  bsum = (int*)(ws + alc((size_t)SCAN_B * 4));
    int*  csr  = (int*)(ws + alc((size_t)ET * 4));
    (void)ws_size; (void)n_in;

    // ---- CSR by dst
    hipMemsetAsync(cnt, 0, (size_t)2 * Nn * 4, stream);
    const int ETB = (ET + 255) / 256;
    count_k<<<ETB, 256, 0, stream>>>(ei + Ee, cnt, Ee, Nn);
    const int nb = (Nn + SCAN_B - 1) / SCAN_B;
    scan1_k<<<nb, SCAN_B, 0, stream>>>(cnt, part, bsum, Nn);
    scan2_k<<<1, SCAN_B, 0, stream>>>(bsum, nb);
    scan3_k<<<nb, SCAN_B, 0, stream>>>(part, bsum, offs, Nn);
    scatter_k<<<ETB, 256, 0, stream>>>(ei, ei + Ee, offs, fill, csr, Ee, Nn);

    const int nwb = (Nn + 3) / 4;   // wave-per-node kernels, 4 waves/block

    // ---- layer 1: GAT(75 -> 4x128, concat) + BN + ReLU
    {
        dim3 grid(512 / 64, (Nn + 63) / 64);
        gemm_k<true><<<grid, 256, 0, stream>>>(x, W1, hA, Nn, FIN, 512);
        logits_k<512, 128><<<nwb, 256, 0, stream>>>(hA, as1, ad1, als, ald, Nn);
        agg_k<512, 128, true><<<nwb, 256, 0, stream>>>(hA, offs, csr, als, ald,
                                                       b1, g1, bt1, rm1, rv1, hB, Nn);
    }
    // ---- layer 2: GAT(512 -> 4x128, concat) + BN + ReLU
    {
        dim3 grid(512 / 64, (Nn + 63) / 64);
        gemm_k<false><<<grid, 256, 0, stream>>>(hB, W2, hA, Nn, 512, 512);
        logits_k<512, 128><<<nwb, 256, 0, stream>>>(hA, as2, ad2, als, ald, Nn);
        agg_k<512, 128, true><<<nwb, 256, 0, stream>>>(hA, offs, csr, als, ald,
                                                       b2, g2, bt2, rm2, rv2, hB, Nn);
    }
    // ---- layer 3: GAT(512 -> 1x128, mean) + BN (no ReLU)
    {
        dim3 grid(128 / 64, (Nn + 63) / 64);
        gemm_k<false><<<grid, 256, 0, stream>>>(hB, W3, hA, Nn, 512, 128);
        logits_k<128, 128><<<nwb, 256, 0, stream>>>(hA, as3, ad3, als, ald, Nn);
        agg_k<128, 128, false><<<nwb, 256, 0, stream>>>(hA, offs, csr, als, ald,
                                                        b3, g3, bt3, rm3, rv3, hB, Nn);
    }
    // ---- global mean+max pool
    pool_k<<<Gg, 128, 0, stream>>>(hB, batch, (float*)d_out, Nn);
}

// Round 3
// 462.416 us; speedup vs baseline: 1.9239x; 1.9239x over previous
//
#include <hip/hip_runtime.h>

typedef unsigned short u16;
typedef unsigned int u32;
typedef __attribute__((ext_vector_type(8))) short s16x8;
typedef __attribute__((ext_vector_type(4))) float f32x4;

__device__ __forceinline__ float bf2f(u32 u) {
    return __uint_as_float(u << 16);
}
__device__ __forceinline__ u16 f2bf(float f) {
    u32 x = __float_as_uint(f);
    u32 r = (x + 0x7fffu + ((x >> 16) & 1u)) >> 16;   // round-nearest-even
    return (u16)r;
}

__device__ __forceinline__ void gload16(const u16* g, u16* l) {
    __builtin_amdgcn_global_load_lds(
        (const __attribute__((address_space(1))) unsigned int*)g,
        (__attribute__((address_space(3))) unsigned int*)l,
        16, 0, 0);
}

// ---------------------------------------------------------------- prep
// x [N][75] f32 -> xb [Mp][96] bf16 (zero-pad cols & rows)
__global__ __launch_bounds__(256) void cvtx_k(
    const float* __restrict__ x, u16* __restrict__ xb, int N, int Mp)
{
    const int i = blockIdx.x * 256 + threadIdx.x;
    if (i >= Mp * 96) return;
    const int r = i / 96, c = i - r * 96;
    float v = (r < N && c < 75) ? x[(size_t)r * 75 + c] : 0.f;
    xb[i] = f2bf(v);
}

// W [K][Ncol] f32 -> Wt [Ncol][Kp] bf16 (transpose, zero-pad K..Kp)
__global__ __launch_bounds__(256) void cvtw_k(
    const float* __restrict__ W, u16* __restrict__ Wt, int K, int Kp, int Ncol)
{
    const int i = blockIdx.x * 256 + threadIdx.x;
    if (i >= Ncol * Kp) return;
    const int n = i / Kp, k = i - n * Kp;
    Wt[i] = f2bf(k < K ? W[(size_t)k * Ncol + n] : 0.f);
}

// ---------------------------------------------------------------- MFMA GEMM
// C[M,Ncol] = A[M,K] @ Bt[Ncol,K]^T ; all bf16, fp32 accum.
// 128x128 tile, BK=32, 256 threads = 4 waves, each wave 64x64 (4x4 frags).
// LDS linear [128][32]; XOR-swizzled 16B groups: slot s holds k-group s^((r>>1)&3).
__global__ __launch_bounds__(256) void mgemm_k(
    const u16* __restrict__ A, const u16* __restrict__ Bt,
    u16* __restrict__ C, int M, int K, int Ncol)
{
    __shared__ u16 Al[128 * 32];
    __shared__ u16 Bl[128 * 32];
    const int t = threadIdx.x;
    const int lane = t & 63;
    const int wid = t >> 6;
    const int wr = wid >> 1, wc = wid & 1;
    const int rr = lane & 15, q = lane >> 4;
    const int m0 = blockIdx.y * 128, n0 = blockIdx.x * 128;

    f32x4 acc[4][4];
#pragma unroll
    for (int m = 0; m < 4; ++m)
#pragma unroll
        for (int n = 0; n < 4; ++n) acc[m][n] = (f32x4){0.f, 0.f, 0.f, 0.f};

    // staging slots: si = i*256+t, row=si>>2, 16B-group s=si&3, source group g=s^key(row)
    const int nk = K >> 5;
    for (int kt = 0; kt < nk; ++kt) {
        const int k0 = kt << 5;
#pragma unroll
        for (int i = 0; i < 2; ++i) {
            const int si = i * 256 + t;
            const int r = si >> 2, s = si & 3;
            const int g = s ^ ((r >> 1) & 3);
            gload16(A  + (size_t)(m0 + r) * K + k0 + g * 8, &Al[si * 8]);
            gload16(Bt + (size_t)(n0 + r) * K + k0 + g * 8, &Bl[si * 8]);
        }
        __syncthreads();
        s16x8 af[4], bf[4];
#pragma unroll
        for (int m = 0; m < 4; ++m) {
            const int r = wr * 64 + m * 16 + rr;
            af[m] = *reinterpret_cast<const s16x8*>(&Al[r * 32 + ((q ^ ((r >> 1) & 3)) << 3)]);
        }
#pragma unroll
        for (int n = 0; n < 4; ++n) {
            const int r = wc * 64 + n * 16 + rr;
            bf[n] = *reinterpret_cast<const s16x8*>(&Bl[r * 32 + ((q ^ ((r >> 1) & 3)) << 3)]);
        }
#pragma unroll
        for (int m = 0; m < 4; ++m)
#pragma unroll
            for (int n = 0; n < 4; ++n)
                acc[m][n] = __builtin_amdgcn_mfma_f32_16x16x32_bf16(af[m], bf[n], acc[m][n], 0, 0, 0);
        __syncthreads();
    }
    // epilogue: C row = (lane>>4)*4+j, col = lane&15 within each 16x16 fragment
#pragma unroll
    for (int m = 0; m < 4; ++m) {
        const int row_b = m0 + wr * 64 + m * 16 + q * 4;
#pragma unroll
        for (int j = 0; j < 4; ++j) {
            const int row = row_b + j;
            if (row < M) {
#pragma unroll
                for (int n = 0; n < 4; ++n) {
                    const int col = n0 + wc * 64 + n * 16 + rr;
                    C[(size_t)row * Ncol + col] = f2bf(acc[m][n][j]);
                }
            }
        }
    }
}

// ---------------------------------------------------------------- logits
// al_s[n,h] = sum_c h[n,h,c]*a_src[h,c]; one wave per node. h bf16, a_* f32.
template<int CH, int C>
__global__ __launch_bounds__(256) void logits_k(
    const u16* __restrict__ h, const float* __restrict__ a_s,
    const float* __restrict__ a_d, float* __restrict__ als,
    float* __restrict__ ald, int N)
{
    constexpr int HH = CH / C;
    constexpr int Kc = CH / 64;
    const int lane = threadIdx.x & 63;
    const int n = blockIdx.x * 4 + (threadIdx.x >> 6);
    if (n >= N) return;
    const int ch0 = Kc * lane;
    float vv[Kc];
    const u16* hp = h + (size_t)n * CH + ch0;
    if constexpr (Kc == 8) {
        const int4 r = *reinterpret_cast<const int4*>(hp);
        const u32 rr[4] = {(u32)r.x, (u32)r.y, (u32)r.z, (u32)r.w};
#pragma unroll
        for (int qq = 0; qq < 4; ++qq) { vv[2*qq] = bf2f(rr[qq] & 0xffffu); vv[2*qq+1] = bf2f(rr[qq] >> 16); }
    } else {
        const u32 r = *reinterpret_cast<const u32*>(hp);
        vv[0] = bf2f(r & 0xffffu); vv[1] = bf2f(r >> 16);
    }
    float ps = 0.f, pd = 0.f;
#pragma unroll
    for (int j = 0; j < Kc; ++j) {
        ps += vv[j] * a_s[ch0 + j];
        pd += vv[j] * a_d[ch0 + j];
    }
    constexpr int Gs = 64 / HH;   // lanes per head group
#pragma unroll
    for (int off = Gs >> 1; off; off >>= 1) {
        ps += __shfl_xor(ps, off, 64);
        pd += __shfl_xor(pd, off, 64);
    }
    const int hd = ch0 / C;
    if ((lane & (Gs - 1)) == 0) {
        als[(size_t)n * HH + hd] = ps;
        ald[(size_t)n * HH + hd] = pd;
    }
}

// ---------------------------------------------------------------- CSR build
__global__ void count_k(const int* __restrict__ edst, int* __restrict__ cnt, int E_, int N_)
{
    const int i = blockIdx.x * 256 + threadIdx.x;
    if (i >= E_ + N_) return;
    const int d = (i < E_) ? edst[i] : (i - E_);
    atomicAdd(&cnt[d], 1);
}

#define SCAN_B 256
__global__ void scan1_k(const int* __restrict__ cnt, int* __restrict__ part,
                        int* __restrict__ bsum, int n)
{
    __shared__ int sm[SCAN_B];
    const int idx = blockIdx.x * SCAN_B + threadIdx.x;
    int v = (idx < n) ? cnt[idx] : 0;
    sm[threadIdx.x] = v;
    __syncthreads();
    for (int off = 1; off < SCAN_B; off <<= 1) {
        int t2 = (threadIdx.x >= off) ? sm[threadIdx.x - off] : 0;
        __syncthreads();
        sm[threadIdx.x] += t2;
        __syncthreads();
    }
    if (idx < n) part[idx] = sm[threadIdx.x];
    if (threadIdx.x == SCAN_B - 1) bsum[blockIdx.x] = sm[threadIdx.x];
}

__global__ void scan2_k(int* __restrict__ bsum, int nb)
{
    __shared__ int sm[SCAN_B];
    const int t = threadIdx.x;
    int v = (t < nb) ? bsum[t] : 0;
    sm[t] = v;
    __syncthreads();
    for (int off = 1; off < SCAN_B; off <<= 1) {
        int t2 = (t >= off) ? sm[t - off] : 0;
        __syncthreads();
        sm[t] += t2;
        __syncthreads();
    }
    if (t < nb) bsum[t] = sm[t] - v;   // exclusive
}

__global__ void scan3_k(const int* __restrict__ part, const int* __restrict__ boff,
                        int* __restrict__ offs, int n)
{
    const int idx = blockIdx.x * SCAN_B + threadIdx.x;
    if (idx < n) offs[idx + 1] = part[idx] + boff[idx / SCAN_B];
    if (idx == 0) offs[0] = 0;
}

__global__ void scatter_k(const int* __restrict__ esrc, const int* __restrict__ edst,
                          const int* __restrict__ offs, int* __restrict__ fill,
                          int* __restrict__ csr, int E_, int N_)
{
    const int i = blockIdx.x * 256 + threadIdx.x;
    if (i >= E_ + N_) return;
    int s, d;
    if (i < E_) { s = esrc[i]; d = edst[i]; } else { s = d = i - E_; }
    const int pos = offs[d] + atomicAdd(&fill[d], 1);
    csr[pos] = s;
}

// ---------------------------------------------------------------- softmax+aggregate+BN(+ReLU)
// one wave per dst node; atomic-free segmented softmax & weighted gather.
template<int CH, int C, bool RELU>
__global__ __launch_bounds__(256) void agg_k(
    const u16* __restrict__ hsrc, const int* __restrict__ offs,
    const int* __restrict__ csr, const float* __restrict__ als,
    const float* __restrict__ ald, const float* __restrict__ bias,
    const float* __restrict__ gam, const float* __restrict__ bet,
    const float* __restrict__ rmean, const float* __restrict__ rvar,
    u16* __restrict__ outp, int N)
{
    constexpr int HH = CH / C;
    constexpr int Kc = CH / 64;
    const int lane = threadIdx.x & 63;
    const int dst = blockIdx.x * 4 + (threadIdx.x >> 6);
    if (dst >= N) return;
    const int ch0 = Kc * lane;
    const int hd = ch0 / C;          // head of this lane's channels (constant)

    float adv[HH];
#pragma unroll
    for (int h = 0; h < HH; ++h) adv[h] = ald[(size_t)dst * HH + h];

    const int rs = offs[dst], re = offs[dst + 1];

    // pass 1: per-head max
    float m[HH];
#pragma unroll
    for (int h = 0; h < HH; ++h) m[h] = -1e30f;
    for (int s = rs + lane; s < re; s += 64) {
        const int sn = csr[s];
        if constexpr (HH == 4) {
            const float4 av = *reinterpret_cast<const float4*>(&als[(size_t)sn * 4]);
            const float ev[4] = {av.x + adv[0], av.y + adv[1], av.z + adv[2], av.w + adv[3]};
#pragma unroll
            for (int h = 0; h < 4; ++h) {
                float e = ev[h]; e = (e > 0.f) ? e : 0.2f * e;
                m[h] = fmaxf(m[h], e);
            }
        } else {
            float e = als[sn] + adv[0]; e = (e > 0.f) ? e : 0.2f * e;
            m[0] = fmaxf(m[0], e);
        }
    }
#pragma unroll
    for (int h = 0; h < HH; ++h)
#pragma unroll
        for (int off = 32; off; off >>= 1) m[h] = fmaxf(m[h], __shfl_xor(m[h], off, 64));

    // pass 2: per-head denom
    float smv[HH];
#pragma unroll
    for (int h = 0; h < HH; ++h) smv[h] = 0.f;
    for (int s = rs + lane; s < re; s += 64) {
        const int sn = csr[s];
        if constexpr (HH == 4) {
            const float4 av = *reinterpret_cast<const float4*>(&als[(size_t)sn * 4]);
            const float ev[4] = {av.x + adv[0], av.y + adv[1], av.z + adv[2], av.w + adv[3]};
#pragma unroll
            for (int h = 0; h < 4; ++h) {
                float e = ev[h]; e = (e > 0.f) ? e : 0.2f * e;
                smv[h] += __expf(e - m[h]);
            }
        } else {
            float e = als[sn] + adv[0]; e = (e > 0.f) ? e : 0.2f * e;
            smv[0] += __expf(e - m[0]);
        }
    }
#pragma unroll
    for (int h = 0; h < HH; ++h)
#pragma unroll
        for (int off = 32; off; off >>= 1) smv[h] += __shfl_xor(smv[h], off, 64);
    float inv[HH];
#pragma unroll
    for (int h = 0; h < HH; ++h) inv[h] = 1.f / (smv[h] + 1e-16f);

    // pass 3: weighted gather (sequential over edges, parallel over channels)
    float acc[Kc] = {};
    for (int s = rs; s < re; ++s) {
        const int sn = csr[s];
        float e = als[(size_t)sn * HH + hd] + adv[hd];
        e = (e > 0.f) ? e : 0.2f * e;
        const float a = __expf(e - m[hd]) * inv[hd];
        const u16* hp = hsrc + (size_t)sn * CH + ch0;
        if constexpr (Kc == 8) {
            const int4 r = *reinterpret_cast<const int4*>(hp);
            const u32 rr2[4] = {(u32)r.x, (u32)r.y, (u32)r.z, (u32)r.w};
#pragma unroll
            for (int qq = 0; qq < 4; ++qq) {
                acc[2*qq]   += a * bf2f(rr2[qq] & 0xffffu);
                acc[2*qq+1] += a * bf2f(rr2[qq] >> 16);
            }
        } else {
            const u32 r = *reinterpret_cast<const u32*>(hp);
            acc[0] += a * bf2f(r & 0xffffu);
            acc[1] += a * bf2f(r >> 16);
        }
    }

    // epilogue: +bias, BN (eval), optional ReLU, store bf16
    u16 ob[Kc];
#pragma unroll
    for (int j = 0; j < Kc; ++j) {
        const int ch = ch0 + j;
        const float scale = gam[ch] * rsqrtf(rvar[ch] + 1e-5f);
        float val = (acc[j] + bias[ch] - rmean[ch]) * scale + bet[ch];
        if (RELU) val = fmaxf(val, 0.f);
        ob[j] = f2bf(val);
    }
    u16* op = outp + (size_t)dst * CH + ch0;
    if constexpr (Kc == 8) {
        int4 w;
        w.x = (int)((u32)ob[0] | ((u32)ob[1] << 16));
        w.y = (int)((u32)ob[2] | ((u32)ob[3] << 16));
        w.z = (int)((u32)ob[4] | ((u32)ob[5] << 16));
        w.w = (int)((u32)ob[6] | ((u32)ob[7] << 16));
        *reinterpret_cast<int4*>(op) = w;
    } else {
        *reinterpret_cast<u32*>(op) = (u32)ob[0] | ((u32)ob[1] << 16);
    }
}

// ---------------------------------------------------------------- pool
__global__ __launch_bounds__(128) void pool_k(
    const u16* __restrict__ h3, const int* __restrict__ batch,
    float* __restrict__ out, int N)
{
    const int g = blockIdx.x;
    const int t = threadIdx.x;
    int lo = 0, hi = N;
    while (lo < hi) { int mid = (lo + hi) >> 1; if (batch[mid] < g) lo = mid + 1; else hi = mid; }
    const int s0 = lo;
    lo = 0; hi = N;
    while (lo < hi) { int mid = (lo + hi) >> 1; if (batch[mid] < g + 1) lo = mid + 1; else hi = mid; }
    const int s1 = lo;
    float sum = 0.f, mx = -1e30f;
    for (int n = s0; n < s1; ++n) {
        const float v = bf2f((u32)h3[(size_t)n * 128 + t]);
        sum += v;
        mx = fmaxf(mx, v);
    }
    const int cnt = s1 - s0;
    out[(size_t)g * 256 + t]       = cnt ? sum / (float)cnt : 0.f;
    out[(size_t)g * 256 + 128 + t] = cnt ? mx : 0.f;
}

// ---------------------------------------------------------------- launch
extern "C" void kernel_launch(void* const* d_in, const int* in_sizes, int n_in,
                              void* d_out, int out_size, void* d_ws, size_t ws_size,
                              hipStream_t stream)
{
    const float* x   = (const float*)d_in[0];
    const int* ei    = (const int*)d_in[1];
    const int* batch = (const int*)d_in[2];
    const float* W1  = (const float*)d_in[3];
    const float* as1 = (const float*)d_in[4];
    const float* ad1 = (const float*)d_in[5];
    const float* b1  = (const float*)d_in[6];
    const float* g1  = (const float*)d_in[7];
    const float* bt1 = (const float*)d_in[8];
    const float* rm1 = (const float*)d_in[9];
    const float* rv1 = (const float*)d_in[10];
    const float* W2  = (const float*)d_in[11];
    const float* as2 = (const float*)d_in[12];
    const float* ad2 = (const float*)d_in[13];
    const float* b2  = (const float*)d_in[14];
    const float* g2  = (const float*)d_in[15];
    const float* bt2 = (const float*)d_in[16];
    const float* rm2 = (const float*)d_in[17];
    const float* rv2 = (const float*)d_in[18];
    const float* W3  = (const float*)d_in[19];
    const float* as3 = (const float*)d_in[20];
    const float* ad3 = (const float*)d_in[21];
    const float* b3  = (const float*)d_in[22];
    const float* g3  = (const float*)d_in[23];
    const float* bt3 = (const float*)d_in[24];
    const float* rm3 = (const float*)d_in[25];
    const float* rv3 = (const float*)d_in[26];

    const int Nn = in_sizes[2];           // 50000
    const int Ee = in_sizes[1] / 2;       // 400000
    const int ET = Ee + Nn;               // + self-loops
    const int Gg = out_size / 256;        // 512
    const int Mp = ((Nn + 127) / 128) * 128;   // 50048 padded rows

    // workspace carve-up (256B aligned)
    char* ws = (char*)d_ws;
    size_t o = 0;
    auto alc = [&](size_t bytes) { size_t r = o; o = (o + bytes + 255) & ~(size_t)255; return r; };
    u16*  hA   = (u16*)(ws + alc((size_t)Mp * 512 * 2));
    u16*  hB   = (u16*)(ws + alc((size_t)Mp * 512 * 2));
    u16*  xb   = (u16*)(ws + alc((size_t)Mp * 96 * 2));
    u16*  Wt1  = (u16*)(ws + alc((size_t)512 * 96 * 2));
    u16*  Wt2  = (u16*)(ws + alc((size_t)512 * 512 * 2));
    u16*  Wt3  = (u16*)(ws + alc((size_t)128 * 512 * 2));
    float* als = (float*)(ws + alc((size_t)Nn * 4 * 4));
    float* ald = (float*)(ws + alc((size_t)Nn * 4 * 4));
    int*  cnt  = (int*)(ws + alc((size_t)2 * Nn * 4));   // cnt + fill adjacent
    int*  fill = cnt + Nn;
    int*  offs = (int*)(ws + alc((size_t)(Nn + 1) * 4));
    int*  part = (int*)(ws + alc((size_t)Nn * 4));
    int*  bsum = (int*)(ws + alc((size_t)SCAN_B * 4));
    int*  csr  = (int*)(ws + alc((size_t)ET * 4));
    (void)ws_size; (void)n_in;

    // ---- CSR by dst
    hipMemsetAsync(cnt, 0, (size_t)2 * Nn * 4, stream);
    const int ETB = (ET + 255) / 256;
    count_k<<<ETB, 256, 0, stream>>>(ei + Ee, cnt, Ee, Nn);
    const int nb = (Nn + SCAN_B - 1) / SCAN_B;
    scan1_k<<<nb, SCAN_B, 0, stream>>>(cnt, part, bsum, Nn);
    scan2_k<<<1, SCAN_B, 0, stream>>>(bsum, nb);
    scan3_k<<<nb, SCAN_B, 0, stream>>>(part, bsum, offs, Nn);
    scatter_k<<<ETB, 256, 0, stream>>>(ei, ei + Ee, offs, fill, csr, Ee, Nn);

    // ---- bf16 prep
    cvtx_k<<<(Mp * 96 + 255) / 256, 256, 0, stream>>>(x, xb, Nn, Mp);
    cvtw_k<<<(512 * 96 + 255) / 256, 256, 0, stream>>>(W1, Wt1, 75, 96, 512);
    cvtw_k<<<(512 * 512 + 255) / 256, 256, 0, stream>>>(W2, Wt2, 512, 512, 512);
    cvtw_k<<<(128 * 512 + 255) / 256, 256, 0, stream>>>(W3, Wt3, 512, 512, 128);

    const int nwb = (Nn + 3) / 4;   // wave-per-node kernels, 4 waves/block
    const int mb = Mp / 128;

    // ---- layer 1: GAT(75 -> 4x128, concat) + BN + ReLU
    {
        dim3 grid(4, mb);
        mgemm_k<<<grid, 256, 0, stream>>>(xb, Wt1, hA, Nn, 96, 512);
        logits_k<512, 128><<<nwb, 256, 0, stream>>>(hA, as1, ad1, als, ald, Nn);
        agg_k<512, 128, true><<<nwb, 256, 0, stream>>>(hA, offs, csr, als, ald,
                                                       b1, g1, bt1, rm1, rv1, hB, Nn);
    }
    // ---- layer 2: GAT(512 -> 4x128, concat) + BN + ReLU
    {
        dim3 grid(4, mb);
        mgemm_k<<<grid, 256, 0, stream>>>(hB, Wt2, hA, Nn, 512, 512);
        logits_k<512, 128><<<nwb, 256, 0, stream>>>(hA, as2, ad2, als, ald, Nn);
        agg_k<512, 128, true><<<nwb, 256, 0, stream>>>(hA, offs, csr, als, ald,
                                                       b2, g2, bt2, rm2, rv2, hB, Nn);
    }
    // ---- layer 3: GAT(512 -> 1x128, mean) + BN (no ReLU)
    {
        dim3 grid(1, mb);
        mgemm_k<<<grid, 256, 0, stream>>>(hB, Wt3, hA, Nn, 512, 128);
        logits_k<128, 128><<<nwb, 256, 0, stream>>>(hA, as3, ad3, als, ald, Nn);
        agg_k<128, 128, false><<<nwb, 256, 0, stream>>>(hA, offs, csr, als, ald,
                                                        b3, g3, bt3, rm3, rv3, hB, Nn);
    }
    // ---- global mean+max pool
    pool_k<<<Gg, 128, 0, stream>>>(hB, batch, (float*)d_out, Nn);
}

// Round 4
// 418.120 us; speedup vs baseline: 2.1277x; 1.1059x over previous
//
#include <hip/hip_runtime.h>

typedef unsigned short u16;
typedef unsigned int u32;
typedef __attribute__((ext_vector_type(8))) short s16x8;
typedef __attribute__((ext_vector_type(4))) float f32x4;

__device__ __forceinline__ float bf2f(u32 u) {
    return __uint_as_float(u << 16);
}
__device__ __forceinline__ u16 f2bf(float f) {
    u32 x = __float_as_uint(f);
    u32 r = (x + 0x7fffu + ((x >> 16) & 1u)) >> 16;   // round-nearest-even
    return (u16)r;
}

__device__ __forceinline__ void gload16(const u16* g, u16* l) {
    __builtin_amdgcn_global_load_lds(
        (const __attribute__((address_space(1))) unsigned int*)g,
        (__attribute__((address_space(3))) unsigned int*)l,
        16, 0, 0);
}

// ---------------------------------------------------------------- prep
__global__ __launch_bounds__(256) void cvtx_k(
    const float* __restrict__ x, u16* __restrict__ xb, int N, int Mp)
{
    const int i = blockIdx.x * 256 + threadIdx.x;
    if (i >= Mp * 96) return;
    const int r = i / 96, c = i - r * 96;
    float v = (r < N && c < 75) ? x[(size_t)r * 75 + c] : 0.f;
    xb[i] = f2bf(v);
}

__global__ __launch_bounds__(256) void cvtw_k(
    const float* __restrict__ W, u16* __restrict__ Wt, int K, int Kp, int Ncol)
{
    const int i = blockIdx.x * 256 + threadIdx.x;
    if (i >= Ncol * Kp) return;
    const int n = i / Kp, k = i - n * Kp;
    Wt[i] = f2bf(k < K ? W[(size_t)k * Ncol + n] : 0.f);
}

// ---------------------------------------------------------------- MFMA GEMM
// C[M,Ncol] = A[M,K] @ Bt[Ncol,K]^T ; all bf16, fp32 accum.
// 128x128 tile, BK=32, 256 threads = 4 waves, each wave 64x64 (4x4 frags).
__global__ __launch_bounds__(256) void mgemm_k(
    const u16* __restrict__ A, const u16* __restrict__ Bt,
    u16* __restrict__ C, int M, int K, int Ncol)
{
    __shared__ u16 Al[128 * 32];
    __shared__ u16 Bl[128 * 32];
    const int t = threadIdx.x;
    const int lane = t & 63;
    const int wid = t >> 6;
    const int wr = wid >> 1, wc = wid & 1;
    const int rr = lane & 15, q = lane >> 4;
    const int m0 = blockIdx.y * 128, n0 = blockIdx.x * 128;

    f32x4 acc[4][4];
#pragma unroll
    for (int m = 0; m < 4; ++m)
#pragma unroll
        for (int n = 0; n < 4; ++n) acc[m][n] = (f32x4){0.f, 0.f, 0.f, 0.f};

    const int nk = K >> 5;
    for (int kt = 0; kt < nk; ++kt) {
        const int k0 = kt << 5;
#pragma unroll
        for (int i = 0; i < 2; ++i) {
            const int si = i * 256 + t;
            const int r = si >> 2, s = si & 3;
            const int g = s ^ ((r >> 1) & 3);
            gload16(A  + (size_t)(m0 + r) * K + k0 + g * 8, &Al[si * 8]);
            gload16(Bt + (size_t)(n0 + r) * K + k0 + g * 8, &Bl[si * 8]);
        }
        __syncthreads();
        s16x8 af[4], bf[4];
#pragma unroll
        for (int m = 0; m < 4; ++m) {
            const int r = wr * 64 + m * 16 + rr;
            af[m] = *reinterpret_cast<const s16x8*>(&Al[r * 32 + ((q ^ ((r >> 1) & 3)) << 3)]);
        }
#pragma unroll
        for (int n = 0; n < 4; ++n) {
            const int r = wc * 64 + n * 16 + rr;
            bf[n] = *reinterpret_cast<const s16x8*>(&Bl[r * 32 + ((q ^ ((r >> 1) & 3)) << 3)]);
        }
#pragma unroll
        for (int m = 0; m < 4; ++m)
#pragma unroll
            for (int n = 0; n < 4; ++n)
                acc[m][n] = __builtin_amdgcn_mfma_f32_16x16x32_bf16(af[m], bf[n], acc[m][n], 0, 0, 0);
        __syncthreads();
    }
#pragma unroll
    for (int m = 0; m < 4; ++m) {
        const int row_b = m0 + wr * 64 + m * 16 + q * 4;
#pragma unroll
        for (int j = 0; j < 4; ++j) {
            const int row = row_b + j;
            if (row < M) {
#pragma unroll
                for (int n = 0; n < 4; ++n) {
                    const int col = n0 + wc * 64 + n * 16 + rr;
                    C[(size_t)row * Ncol + col] = f2bf(acc[m][n][j]);
                }
            }
        }
    }
}

// ---------------------------------------------------------------- logits
template<int CH, int C>
__global__ __launch_bounds__(256) void logits_k(
    const u16* __restrict__ h, const float* __restrict__ a_s,
    const float* __restrict__ a_d, float* __restrict__ als,
    float* __restrict__ ald, int N)
{
    constexpr int HH = CH / C;
    constexpr int Kc = CH / 64;
    const int lane = threadIdx.x & 63;
    const int n = blockIdx.x * 4 + (threadIdx.x >> 6);
    if (n >= N) return;
    const int ch0 = Kc * lane;
    float vv[Kc];
    const u16* hp = h + (size_t)n * CH + ch0;
    if constexpr (Kc == 8) {
        const int4 r = *reinterpret_cast<const int4*>(hp);
        const u32 rr[4] = {(u32)r.x, (u32)r.y, (u32)r.z, (u32)r.w};
#pragma unroll
        for (int qq = 0; qq < 4; ++qq) { vv[2*qq] = bf2f(rr[qq] & 0xffffu); vv[2*qq+1] = bf2f(rr[qq] >> 16); }
    } else {
        const u32 r = *reinterpret_cast<const u32*>(hp);
        vv[0] = bf2f(r & 0xffffu); vv[1] = bf2f(r >> 16);
    }
    float ps = 0.f, pd = 0.f;
#pragma unroll
    for (int j = 0; j < Kc; ++j) {
        ps += vv[j] * a_s[ch0 + j];
        pd += vv[j] * a_d[ch0 + j];
    }
    constexpr int Gs = 64 / HH;
#pragma unroll
    for (int off = Gs >> 1; off; off >>= 1) {
        ps += __shfl_xor(ps, off, 64);
        pd += __shfl_xor(pd, off, 64);
    }
    const int hd = ch0 / C;
    if ((lane & (Gs - 1)) == 0) {
        als[(size_t)n * HH + hd] = ps;
        ald[(size_t)n * HH + hd] = pd;
    }
}

// ---------------------------------------------------------------- CSR build
__global__ void count_k(const int* __restrict__ edst, int* __restrict__ cnt, int E_, int N_)
{
    const int i = blockIdx.x * 256 + threadIdx.x;
    if (i >= E_ + N_) return;
    const int d = (i < E_) ? edst[i] : (i - E_);
    atomicAdd(&cnt[d], 1);
}

#define SCAN_B 256
__global__ void scan1_k(const int* __restrict__ cnt, int* __restrict__ part,
                        int* __restrict__ bsum, int n)
{
    __shared__ int sm[SCAN_B];
    const int idx = blockIdx.x * SCAN_B + threadIdx.x;
    int v = (idx < n) ? cnt[idx] : 0;
    sm[threadIdx.x] = v;
    __syncthreads();
    for (int off = 1; off < SCAN_B; off <<= 1) {
        int t2 = (threadIdx.x >= off) ? sm[threadIdx.x - off] : 0;
        __syncthreads();
        sm[threadIdx.x] += t2;
        __syncthreads();
    }
    if (idx < n) part[idx] = sm[threadIdx.x];
    if (threadIdx.x == SCAN_B - 1) bsum[blockIdx.x] = sm[threadIdx.x];
}

__global__ void scan2_k(int* __restrict__ bsum, int nb)
{
    __shared__ int sm[SCAN_B];
    const int t = threadIdx.x;
    int v = (t < nb) ? bsum[t] : 0;
    sm[t] = v;
    __syncthreads();
    for (int off = 1; off < SCAN_B; off <<= 1) {
        int t2 = (t >= off) ? sm[t - off] : 0;
        __syncthreads();
        sm[t] += t2;
        __syncthreads();
    }
    if (t < nb) bsum[t] = sm[t] - v;   // exclusive
}

__global__ void scan3_k(const int* __restrict__ part, const int* __restrict__ boff,
                        int* __restrict__ offs, int n)
{
    const int idx = blockIdx.x * SCAN_B + threadIdx.x;
    if (idx < n) offs[idx + 1] = part[idx] + boff[idx / SCAN_B];
    if (idx == 0) offs[0] = 0;
}

__global__ void scatter_k(const int* __restrict__ esrc, const int* __restrict__ edst,
                          const int* __restrict__ offs, int* __restrict__ fill,
                          int* __restrict__ csr, int E_, int N_)
{
    const int i = blockIdx.x * 256 + threadIdx.x;
    if (i >= E_ + N_) return;
    int s, d;
    if (i < E_) { s = esrc[i]; d = edst[i]; } else { s = d = i - E_; }
    const int pos = offs[d] + atomicAdd(&fill[d], 1);
    csr[pos] = s;
}

// ---------------------------------------------------------------- softmax+aggregate+BN(+ReLU)
// one wave per dst node; pass 3 unrolled x4 for memory-level parallelism.
template<int CH, int C, bool RELU>
__global__ __launch_bounds__(256) void agg_k(
    const u16* __restrict__ hsrc, const int* __restrict__ offs,
    const int* __restrict__ csr, const float* __restrict__ als,
    const float* __restrict__ ald, const float* __restrict__ bias,
    const float* __restrict__ gam, const float* __restrict__ bet,
    const float* __restrict__ rmean, const float* __restrict__ rvar,
    u16* __restrict__ outp, int N)
{
    constexpr int HH = CH / C;
    constexpr int Kc = CH / 64;
    const int lane = threadIdx.x & 63;
    const int dst = blockIdx.x * 4 + (threadIdx.x >> 6);
    if (dst >= N) return;
    const int ch0 = Kc * lane;
    const int hd = ch0 / C;

    float adv[HH];
#pragma unroll
    for (int h = 0; h < HH; ++h) adv[h] = ald[(size_t)dst * HH + h];

    const int rs = offs[dst], re = offs[dst + 1];

    // pass 1: per-head max (lane-parallel over edges)
    float m[HH];
#pragma unroll
    for (int h = 0; h < HH; ++h) m[h] = -1e30f;
    for (int s = rs + lane; s < re; s += 64) {
        const int sn = csr[s];
        if constexpr (HH == 4) {
            const float4 av = *reinterpret_cast<const float4*>(&als[(size_t)sn * 4]);
            const float ev[4] = {av.x + adv[0], av.y + adv[1], av.z + adv[2], av.w + adv[3]};
#pragma unroll
            for (int h = 0; h < 4; ++h) {
                float e = ev[h]; e = (e > 0.f) ? e : 0.2f * e;
                m[h] = fmaxf(m[h], e);
            }
        } else {
            float e = als[sn] + adv[0]; e = (e > 0.f) ? e : 0.2f * e;
            m[0] = fmaxf(m[0], e);
        }
    }
#pragma unroll
    for (int h = 0; h < HH; ++h)
#pragma unroll
        for (int off = 32; off; off >>= 1) m[h] = fmaxf(m[h], __shfl_xor(m[h], off, 64));

    // pass 2: per-head denom
    float smv[HH];
#pragma unroll
    for (int h = 0; h < HH; ++h) smv[h] = 0.f;
    for (int s = rs + lane; s < re; s += 64) {
        const int sn = csr[s];
        if constexpr (HH == 4) {
            const float4 av = *reinterpret_cast<const float4*>(&als[(size_t)sn * 4]);
            const float ev[4] = {av.x + adv[0], av.y + adv[1], av.z + adv[2], av.w + adv[3]};
#pragma unroll
            for (int h = 0; h < 4; ++h) {
                float e = ev[h]; e = (e > 0.f) ? e : 0.2f * e;
                smv[h] += __expf(e - m[h]);
            }
        } else {
            float e = als[sn] + adv[0]; e = (e > 0.f) ? e : 0.2f * e;
            smv[0] += __expf(e - m[0]);
        }
    }
#pragma unroll
    for (int h = 0; h < HH; ++h)
#pragma unroll
        for (int off = 32; off; off >>= 1) smv[h] += __shfl_xor(smv[h], off, 64);
    float inv[HH];
#pragma unroll
    for (int h = 0; h < HH; ++h) inv[h] = 1.f / (smv[h] + 1e-16f);

    const float mh = m[hd], invh = inv[hd], advh = adv[hd];

    // pass 3: weighted gather, 4 edges in flight
    float acc[Kc] = {};
    int s = rs;
    for (; s + 4 <= re; s += 4) {
        int sn[4];
#pragma unroll
        for (int u = 0; u < 4; ++u) sn[u] = csr[s + u];
        // issue the 4 big loads first (independent)
        if constexpr (Kc == 8) {
            int4 r[4];
#pragma unroll
            for (int u = 0; u < 4; ++u)
                r[u] = *reinterpret_cast<const int4*>(hsrc + (size_t)sn[u] * CH + ch0);
            float aa[4];
#pragma unroll
            for (int u = 0; u < 4; ++u) {
                float e = als[(size_t)sn[u] * HH + hd] + advh;
                e = (e > 0.f) ? e : 0.2f * e;
                aa[u] = __expf(e - mh) * invh;
            }
#pragma unroll
            for (int u = 0; u < 4; ++u) {
                const u32 rr2[4] = {(u32)r[u].x, (u32)r[u].y, (u32)r[u].z, (u32)r[u].w};
#pragma unroll
                for (int qq = 0; qq < 4; ++qq) {
                    acc[2*qq]   += aa[u] * bf2f(rr2[qq] & 0xffffu);
                    acc[2*qq+1] += aa[u] * bf2f(rr2[qq] >> 16);
                }
            }
        } else {
            u32 r[4];
#pragma unroll
            for (int u = 0; u < 4; ++u)
                r[u] = *reinterpret_cast<const u32*>(hsrc + (size_t)sn[u] * CH + ch0);
            float aa[4];
#pragma unroll
            for (int u = 0; u < 4; ++u) {
                float e = als[sn[u]] + advh;
                e = (e > 0.f) ? e : 0.2f * e;
                aa[u] = __expf(e - mh) * invh;
            }
#pragma unroll
            for (int u = 0; u < 4; ++u) {
                acc[0] += aa[u] * bf2f(r[u] & 0xffffu);
                acc[1] += aa[u] * bf2f(r[u] >> 16);
            }
        }
    }
    for (; s < re; ++s) {
        const int sn = csr[s];
        float e = als[(size_t)sn * HH + hd] + advh;
        e = (e > 0.f) ? e : 0.2f * e;
        const float a = __expf(e - mh) * invh;
        const u16* hp = hsrc + (size_t)sn * CH + ch0;
        if constexpr (Kc == 8) {
            const int4 r = *reinterpret_cast<const int4*>(hp);
            const u32 rr2[4] = {(u32)r.x, (u32)r.y, (u32)r.z, (u32)r.w};
#pragma unroll
            for (int qq = 0; qq < 4; ++qq) {
                acc[2*qq]   += a * bf2f(rr2[qq] & 0xffffu);
                acc[2*qq+1] += a * bf2f(rr2[qq] >> 16);
            }
        } else {
            const u32 r = *reinterpret_cast<const u32*>(hp);
            acc[0] += a * bf2f(r & 0xffffu);
            acc[1] += a * bf2f(r >> 16);
        }
    }

    // epilogue: +bias, BN (eval), optional ReLU, store bf16
    u16 ob[Kc];
#pragma unroll
    for (int j = 0; j < Kc; ++j) {
        const int ch = ch0 + j;
        const float scale = gam[ch] * rsqrtf(rvar[ch] + 1e-5f);
        float val = (acc[j] + bias[ch] - rmean[ch]) * scale + bet[ch];
        if (RELU) val = fmaxf(val, 0.f);
        ob[j] = f2bf(val);
    }
    u16* op = outp + (size_t)dst * CH + ch0;
    if constexpr (Kc == 8) {
        int4 w;
        w.x = (int)((u32)ob[0] | ((u32)ob[1] << 16));
        w.y = (int)((u32)ob[2] | ((u32)ob[3] << 16));
        w.z = (int)((u32)ob[4] | ((u32)ob[5] << 16));
        w.w = (int)((u32)ob[6] | ((u32)ob[7] << 16));
        *reinterpret_cast<int4*>(op) = w;
    } else {
        *reinterpret_cast<u32*>(op) = (u32)ob[0] | ((u32)ob[1] << 16);
    }
}

// ---------------------------------------------------------------- pool
__global__ __launch_bounds__(128) void pool_k(
    const u16* __restrict__ h3, const int* __restrict__ batch,
    float* __restrict__ out, int N)
{
    const int g = blockIdx.x;
    const int t = threadIdx.x;
    int lo = 0, hi = N;
    while (lo < hi) { int mid = (lo + hi) >> 1; if (batch[mid] < g) lo = mid + 1; else hi = mid; }
    const int s0 = lo;
    lo = 0; hi = N;
    while (lo < hi) { int mid = (lo + hi) >> 1; if (batch[mid] < g + 1) lo = mid + 1; else hi = mid; }
    const int s1 = lo;
    float sum = 0.f, mx = -1e30f;
    for (int n = s0; n < s1; ++n) {
        const float v = bf2f((u32)h3[(size_t)n * 128 + t]);
        sum += v;
        mx = fmaxf(mx, v);
    }
    const int cnt = s1 - s0;
    out[(size_t)g * 256 + t]       = cnt ? sum / (float)cnt : 0.f;
    out[(size_t)g * 256 + 128 + t] = cnt ? mx : 0.f;
}

// ---------------------------------------------------------------- launch
extern "C" void kernel_launch(void* const* d_in, const int* in_sizes, int n_in,
                              void* d_out, int out_size, void* d_ws, size_t ws_size,
                              hipStream_t stream)
{
    const float* x   = (const float*)d_in[0];
    const int* ei    = (const int*)d_in[1];
    const int* batch = (const int*)d_in[2];
    const float* W1  = (const float*)d_in[3];
    const float* as1 = (const float*)d_in[4];
    const float* ad1 = (const float*)d_in[5];
    const float* b1  = (const float*)d_in[6];
    const float* g1  = (const float*)d_in[7];
    const float* bt1 = (const float*)d_in[8];
    const float* rm1 = (const float*)d_in[9];
    const float* rv1 = (const float*)d_in[10];
    const float* W2  = (const float*)d_in[11];
    const float* as2 = (const float*)d_in[12];
    const float* ad2 = (const float*)d_in[13];
    const float* b2  = (const float*)d_in[14];
    const float* g2  = (const float*)d_in[15];
    const float* bt2 = (const float*)d_in[16];
    const float* rm2 = (const float*)d_in[17];
    const float* rv2 = (const float*)d_in[18];
    const float* W3  = (const float*)d_in[19];
    const float* as3 = (const float*)d_in[20];
    const float* ad3 = (const float*)d_in[21];
    const float* b3  = (const float*)d_in[22];
    const float* g3  = (const float*)d_in[23];
    const float* bt3 = (const float*)d_in[24];
    const float* rm3 = (const float*)d_in[25];
    const float* rv3 = (const float*)d_in[26];

    const int Nn = in_sizes[2];           // 50000
    const int Ee = in_sizes[1] / 2;       // 400000
    const int ET = Ee + Nn;               // + self-loops
    const int Gg = out_size / 256;        // 512
    const int Mp = ((Nn + 127) / 128) * 128;   // 50048 padded rows

    // workspace carve-up (256B aligned)
    char* ws = (char*)d_ws;
    size_t o = 0;
    auto alc = [&](size_t bytes) { size_t r = o; o = (o + bytes + 255) & ~(size_t)255; return r; };
    u16*  hA   = (u16*)(ws + alc((size_t)Mp * 512 * 2));
    u16*  hB   = (u16*)(ws + alc((size_t)Mp * 512 * 2));
    u16*  xb   = (u16*)(ws + alc((size_t)Mp * 96 * 2));
    u16*  Wt1  = (u16*)(ws + alc((size_t)512 * 96 * 2));
    u16*  Wt2  = (u16*)(ws + alc((size_t)512 * 512 * 2));
    u16*  Wt3  = (u16*)(ws + alc((size_t)128 * 512 * 2));
    float* als = (float*)(ws + alc((size_t)Nn * 4 * 4));
    float* ald = (float*)(ws + alc((size_t)Nn * 4 * 4));
    int*  cnt  = (int*)(ws + alc((size_t)2 * Nn * 4));
    int*  fill = cnt + Nn;
    int*  offs = (int*)(ws + alc((size_t)(Nn + 1) * 4));
    int*  part = (int*)(ws + alc((size_t)Nn * 4));
    int*  bsum = (int*)(ws + alc((size_t)SCAN_B * 4));
    int*  csr  = (int*)(ws + alc((size_t)ET * 4));
    (void)ws_size; (void)n_in;

    // ---- CSR by dst
    hipMemsetAsync(cnt, 0, (size_t)2 * Nn * 4, stream);
    const int ETB = (ET + 255) / 256;
    count_k<<<ETB, 256, 0, stream>>>(ei + Ee, cnt, Ee, Nn);
    const int nb = (Nn + SCAN_B - 1) / SCAN_B;
    scan1_k<<<nb, SCAN_B, 0, stream>>>(cnt, part, bsum, Nn);
    scan2_k<<<1, SCAN_B, 0, stream>>>(bsum, nb);
    scan3_k<<<nb, SCAN_B, 0, stream>>>(part, bsum, offs, Nn);
    scatter_k<<<ETB, 256, 0, stream>>>(ei, ei + Ee, offs, fill, csr, Ee, Nn);

    // ---- bf16 prep
    cvtx_k<<<(Mp * 96 + 255) / 256, 256, 0, stream>>>(x, xb, Nn, Mp);
    cvtw_k<<<(512 * 96 + 255) / 256, 256, 0, stream>>>(W1, Wt1, 75, 96, 512);
    cvtw_k<<<(512 * 512 + 255) / 256, 256, 0, stream>>>(W2, Wt2, 512, 512, 512);
    cvtw_k<<<(128 * 512 + 255) / 256, 256, 0, stream>>>(W3, Wt3, 512, 512, 128);

    const int nwb = (Nn + 3) / 4;
    const int mb = Mp / 128;

    // ---- layer 1
    {
        dim3 grid(4, mb);
        mgemm_k<<<grid, 256, 0, stream>>>(xb, Wt1, hA, Nn, 96, 512);
        logits_k<512, 128><<<nwb, 256, 0, stream>>>(hA, as1, ad1, als, ald, Nn);
        agg_k<512, 128, true><<<nwb, 256, 0, stream>>>(hA, offs, csr, als, ald,
                                                       b1, g1, bt1, rm1, rv1, hB, Nn);
    }
    // ---- layer 2
    {
        dim3 grid(4, mb);
        mgemm_k<<<grid, 256, 0, stream>>>(hB, Wt2, hA, Nn, 512, 512);
        logits_k<512, 128><<<nwb, 256, 0, stream>>>(hA, as2, ad2, als, ald, Nn);
        agg_k<512, 128, true><<<nwb, 256, 0, stream>>>(hA, offs, csr, als, ald,
                                                       b2, g2, bt2, rm2, rv2, hB, Nn);
    }
    // ---- layer 3
    {
        dim3 grid(1, mb);
        mgemm_k<<<grid, 256, 0, stream>>>(hB, Wt3, hA, Nn, 512, 128);
        logits_k<128, 128><<<nwb, 256, 0, stream>>>(hA, as3, ad3, als, ald, Nn);
        agg_k<128, 128, false><<<nwb, 256, 0, stream>>>(hA, offs, csr, als, ald,
                                                        b3, g3, bt3, rm3, rv3, hB, Nn);
    }
    // ---- global mean+max pool
    pool_k<<<Gg, 128, 0, stream>>>(hB, batch, (float*)d_out, Nn);
}